// Round 1
// baseline (743.086 us; speedup 1.0000x reference)
//
#include <hip/hip_runtime.h>
#include <math.h>

#define L_MAX 2048
#define BATCH 64
#define DIM   256
#define CCH   512

// ws layout (floats):
//   hq      : [0, 16384)            (64 x 256)
//   wf      : [16384, 17152)        (3 x 256)
//   sums    : [17152, 17216)        (64)
//   hard_raw: [17216, 148288)       (2048 x 64)
#define HQ_OFF   0
#define WF_OFF   16384
#define SUMS_OFF 17152
#define HARD_OFF 17216

__device__ __forceinline__ float fast_tanh(float x) {
    float ax = fabsf(x);
    float e  = __expf(2.0f * ax);                       // v_exp_f32; inf for big ax -> r=1
    float r  = 1.0f - 2.0f * __builtin_amdgcn_rcpf(e + 1.0f);
    return copysignf(r, x);
}

// Kernel A: hq[b][d] = sum_k ht_query[b][k]*W_query[d][k]
//           wf[j][d] = sum_c W_conv[c][0][j]*W_att_past[d][c]
__global__ __launch_bounds__(256) void prep_kernel(
    const float* __restrict__ ht_query, const float* __restrict__ W_query,
    const float* __restrict__ W_conv,   const float* __restrict__ W_att_past,
    float* __restrict__ hq, float* __restrict__ wf) {
    int t   = threadIdx.x;
    int blk = blockIdx.x;
    __shared__ float q[DIM];
    if (blk < BATCH) {
        q[t] = ht_query[blk * DIM + t];
        __syncthreads();
        const float* wrow = W_query + t * DIM;
        float acc = 0.f;
        #pragma unroll 4
        for (int k = 0; k < DIM; k++) acc += q[k] * wrow[k];
        hq[blk * DIM + t] = acc;
    } else {
        int j = blk - BATCH;
        const float* wrow = W_att_past + t * CCH;
        float acc = 0.f;
        #pragma unroll 4
        for (int c = 0; c < CCH; c++) acc += W_conv[c * 3 + j] * wrow[c];
        wf[j * DIM + t] = acc;
    }
}

// Kernel B: one wave per (l,b) pair. 64 lanes x float4 cover D=256.
// score = sum_d W_attn[d]*tanh(ctx_key + hq + conv-proj) + b_attn
// hard_raw[l*64+b] = (score>=0) ? ctx_mask : 0 ; atomic Z per b.
__global__ __launch_bounds__(256) void score_kernel(
    const float* __restrict__ ctx_key, const float* __restrict__ ctx_mask,
    const float* __restrict__ att_past,
    const float* __restrict__ hq, const float* __restrict__ wf,
    const float* __restrict__ b_att_past, const float* __restrict__ W_attn,
    const float* __restrict__ b_attn,
    float* __restrict__ hard_raw, float* __restrict__ sums) {
    int w    = threadIdx.x >> 6;
    int lane = threadIdx.x & 63;
    int p    = blockIdx.x * 4 + w;         // p = l*64 + b
    int l    = p >> 6;
    int b    = p & 63;
    int d0   = lane << 2;

    float4 k4  = *(const float4*)(ctx_key + (size_t)p * DIM + d0);
    float4 hq4 = *(const float4*)(hq + b * DIM + d0);
    float4 w0  = *(const float4*)(wf + d0);
    float4 w1  = *(const float4*)(wf + DIM + d0);
    float4 w2  = *(const float4*)(wf + 2 * DIM + d0);
    float4 bp  = *(const float4*)(b_att_past + d0);
    float4 wa  = *(const float4*)(W_attn + d0);

    const float* apb = att_past + b * L_MAX;
    float am = (l > 0)         ? apb[l - 1] : 0.f;
    float a0 = apb[l];
    float a1 = (l < L_MAX - 1) ? apb[l + 1] : 0.f;

    float partial;
    {
        float x0 = k4.x + hq4.x + am * w0.x + a0 * w1.x + a1 * w2.x + bp.x;
        float x1 = k4.y + hq4.y + am * w0.y + a0 * w1.y + a1 * w2.y + bp.y;
        float x2 = k4.z + hq4.z + am * w0.z + a0 * w1.z + a1 * w2.z + bp.z;
        float x3 = k4.w + hq4.w + am * w0.w + a0 * w1.w + a1 * w2.w + bp.w;
        partial = fast_tanh(x0) * wa.x + fast_tanh(x1) * wa.y +
                  fast_tanh(x2) * wa.z + fast_tanh(x3) * wa.w;
    }
    #pragma unroll
    for (int off = 32; off > 0; off >>= 1)
        partial += __shfl_xor(partial, off, 64);

    if (lane == 0) {
        float score = partial + b_attn[0];
        float h = (score >= 0.f) ? ctx_mask[p] : 0.f;
        hard_raw[p] = h;
        if (h != 0.f) atomicAdd(&sums[b], h);
    }
}

// Kernel C: ct[b][d] = (1/(Z_b+1e-10)) * sum_l ctx_val[l][b][d]*hard_raw[l][b]
// grid = 64 b * 32 l-chunks; block = 256 (4 waves x 16 l's each).
__global__ __launch_bounds__(256) void ct_kernel(
    const float* __restrict__ ctx_val, const float* __restrict__ hard_raw,
    const float* __restrict__ sums, float* __restrict__ ct) {
    int b     = blockIdx.x >> 5;
    int chunk = blockIdx.x & 31;
    int w     = threadIdx.x >> 6;
    int lane  = threadIdx.x & 63;
    int d0    = lane << 2;
    int l0    = chunk * 64 + w * 16;

    float4 acc = make_float4(0.f, 0.f, 0.f, 0.f);
    for (int i = 0; i < 16; i++) {
        int l = l0 + i;
        float h = hard_raw[l * BATCH + b];
        if (h != 0.f) {                    // wave-uniform: skips the whole 1KB load
            float4 v = *(const float4*)(ctx_val + (size_t)(l * BATCH + b) * DIM + d0);
            acc.x += v.x * h; acc.y += v.y * h;
            acc.z += v.z * h; acc.w += v.w * h;
        }
    }
    __shared__ float red[4 * DIM];
    *(float4*)(red + w * DIM + d0) = acc;
    __syncthreads();
    int d = threadIdx.x;
    float s = red[d] + red[DIM + d] + red[2 * DIM + d] + red[3 * DIM + d];
    float invZ = 1.0f / (sums[b] + 1e-10f);
    atomicAdd(&ct[b * DIM + d], s * invZ);
}

// Kernel D: out_hard[l][b] = hard_raw[l][b] / (Z_b + 1e-10)
__global__ __launch_bounds__(256) void norm_kernel(
    const float* __restrict__ hard_raw, const float* __restrict__ sums,
    float* __restrict__ out_hard) {
    int i = blockIdx.x * blockDim.x + threadIdx.x;   // 0..32767, 4 elems each
    float4 h = *(const float4*)(hard_raw + (size_t)i * 4);
    int b0 = (i * 4) & 63;
    float4 o;
    o.x = h.x / (sums[b0 + 0] + 1e-10f);
    o.y = h.y / (sums[b0 + 1] + 1e-10f);
    o.z = h.z / (sums[b0 + 2] + 1e-10f);
    o.w = h.w / (sums[b0 + 3] + 1e-10f);
    *(float4*)(out_hard + (size_t)i * 4) = o;
}

extern "C" void kernel_launch(void* const* d_in, const int* in_sizes, int n_in,
                              void* d_out, int out_size, void* d_ws, size_t ws_size,
                              hipStream_t stream) {
    const float* ctx_val    = (const float*)d_in[0];
    const float* ctx_key    = (const float*)d_in[1];
    const float* ctx_mask   = (const float*)d_in[2];
    const float* att_past   = (const float*)d_in[3];
    const float* ht_query   = (const float*)d_in[4];
    const float* W_conv     = (const float*)d_in[5];
    const float* W_query    = (const float*)d_in[6];
    const float* W_att_past = (const float*)d_in[7];
    const float* b_att_past = (const float*)d_in[8];
    const float* W_attn     = (const float*)d_in[9];
    const float* b_attn     = (const float*)d_in[10];

    float* ws   = (float*)d_ws;
    float* hq   = ws + HQ_OFF;
    float* wf   = ws + WF_OFF;
    float* sums = ws + SUMS_OFF;
    float* hard = ws + HARD_OFF;

    float* out_ct   = (float*)d_out;            // (64,256)
    float* out_hard = (float*)d_out + BATCH * DIM;  // (2048,64)

    hipMemsetAsync(sums, 0, BATCH * sizeof(float), stream);
    hipMemsetAsync(out_ct, 0, BATCH * DIM * sizeof(float), stream);

    prep_kernel<<<BATCH + 3, 256, 0, stream>>>(ht_query, W_query, W_conv, W_att_past, hq, wf);

    score_kernel<<<(L_MAX * BATCH) / 4, 256, 0, stream>>>(
        ctx_key, ctx_mask, att_past, hq, wf, b_att_past, W_attn, b_attn, hard, sums);

    ct_kernel<<<BATCH * 32, 256, 0, stream>>>(ctx_val, hard, sums, out_ct);

    norm_kernel<<<(L_MAX * BATCH) / (4 * 256), 256, 0, stream>>>(hard, sums, out_hard);
}

// Round 2
// 336.467 us; speedup vs baseline: 2.2085x; 2.2085x over previous
//
#include <hip/hip_runtime.h>
#include <math.h>

#define L_MAX 2048
#define BATCH 64
#define DIM   256
#define CCH   512

// ws layout (floats):
#define HQ_OFF   0          // 64*256      = 16384
#define WF_OFF   16384      // 3*256       = 768
#define SUMS_OFF 17152      // 64*32 padded (one cache line per b) = 2048
#define HARD_OFF 19200      // 2048*64     = 131072
#define PART_OFF 150272     // 32*64*256   = 524288
#define SUMS_STRIDE 32

__device__ __forceinline__ float fast_tanh(float x) {
    float ax = fabsf(x);
    float e  = __expf(2.0f * ax);                       // inf for big ax -> r=1
    float r  = 1.0f - 2.0f * __builtin_amdgcn_rcpf(e + 1.0f);
    return copysignf(r, x);
}

// Kernel A: hq[b][d] = sum_k ht_query[b][k]*W_query[d][k]
//           wf[j][d] = sum_c W_conv[c][0][j]*W_att_past[d][c]
__global__ __launch_bounds__(256) void prep_kernel(
    const float* __restrict__ ht_query, const float* __restrict__ W_query,
    const float* __restrict__ W_conv,   const float* __restrict__ W_att_past,
    float* __restrict__ hq, float* __restrict__ wf) {
    int t   = threadIdx.x;
    int blk = blockIdx.x;
    __shared__ float q[DIM];
    if (blk < BATCH) {
        q[t] = ht_query[blk * DIM + t];
        __syncthreads();
        const float4* wrow = (const float4*)(W_query + t * DIM);
        float acc = 0.f;
        #pragma unroll 8
        for (int k = 0; k < DIM / 4; k++) {
            float4 wv = wrow[k];
            acc += q[4*k] * wv.x + q[4*k+1] * wv.y + q[4*k+2] * wv.z + q[4*k+3] * wv.w;
        }
        hq[blk * DIM + t] = acc;
    } else {
        int j = blk - BATCH;
        const float4* wrow = (const float4*)(W_att_past + t * CCH);
        float acc = 0.f;
        #pragma unroll 8
        for (int c = 0; c < CCH / 4; c++) {
            float4 wv = wrow[c];
            acc += W_conv[(4*c  ) * 3 + j] * wv.x + W_conv[(4*c+1) * 3 + j] * wv.y
                 + W_conv[(4*c+2) * 3 + j] * wv.z + W_conv[(4*c+3) * 3 + j] * wv.w;
        }
        wf[j * DIM + t] = acc;
    }
}

// Kernel B: block = (b, chunk of 64 l's); 4 waves x 16 rows each.
// Per-wave constants hoisted; rows processed 4-at-a-time for ILP.
// One padded atomic per block for Z_b.
__global__ __launch_bounds__(256) void score_kernel(
    const float* __restrict__ ctx_key, const float* __restrict__ ctx_mask,
    const float* __restrict__ att_past,
    const float* __restrict__ hq, const float* __restrict__ wf,
    const float* __restrict__ b_att_past, const float* __restrict__ W_attn,
    const float* __restrict__ b_attn,
    float* __restrict__ hard_raw, float* __restrict__ sums) {
    int b     = blockIdx.x & 63;
    int chunk = blockIdx.x >> 6;
    int w     = threadIdx.x >> 6;
    int lane  = threadIdx.x & 63;
    int d0    = lane << 2;
    int l0    = chunk * 64 + w * 16;

    float4 hq4 = *(const float4*)(hq + b * DIM + d0);
    float4 bp  = *(const float4*)(b_att_past + d0);
    hq4.x += bp.x; hq4.y += bp.y; hq4.z += bp.z; hq4.w += bp.w;
    float4 w0  = *(const float4*)(wf + d0);
    float4 w1  = *(const float4*)(wf + DIM + d0);
    float4 w2  = *(const float4*)(wf + 2 * DIM + d0);
    float4 wa  = *(const float4*)(W_attn + d0);
    float battn = b_attn[0];
    const float* apb = att_past + b * L_MAX;

    float cnt = 0.f;
    for (int i = 0; i < 16; i += 4) {
        float4 k4[4];
        float am[4], a0[4], a1[4];
        #pragma unroll
        for (int j = 0; j < 4; j++) {
            int l = l0 + i + j;
            k4[j] = *(const float4*)(ctx_key + (size_t)(l * BATCH + b) * DIM + d0);
            am[j] = (l > 0)         ? apb[l - 1] : 0.f;
            a0[j] = apb[l];
            a1[j] = (l < L_MAX - 1) ? apb[l + 1] : 0.f;
        }
        float p[4];
        #pragma unroll
        for (int j = 0; j < 4; j++) {
            float x0 = k4[j].x + hq4.x + am[j] * w0.x + a0[j] * w1.x + a1[j] * w2.x;
            float x1 = k4[j].y + hq4.y + am[j] * w0.y + a0[j] * w1.y + a1[j] * w2.y;
            float x2 = k4[j].z + hq4.z + am[j] * w0.z + a0[j] * w1.z + a1[j] * w2.z;
            float x3 = k4[j].w + hq4.w + am[j] * w0.w + a0[j] * w1.w + a1[j] * w2.w;
            p[j] = fast_tanh(x0) * wa.x + fast_tanh(x1) * wa.y +
                   fast_tanh(x2) * wa.z + fast_tanh(x3) * wa.w;
        }
        #pragma unroll
        for (int off = 32; off > 0; off >>= 1) {
            p[0] += __shfl_xor(p[0], off, 64);
            p[1] += __shfl_xor(p[1], off, 64);
            p[2] += __shfl_xor(p[2], off, 64);
            p[3] += __shfl_xor(p[3], off, 64);
        }
        if (lane == 0) {
            #pragma unroll
            for (int j = 0; j < 4; j++) {
                int l = l0 + i + j;
                float h = (p[j] + battn >= 0.f) ? ctx_mask[l * BATCH + b] : 0.f;
                hard_raw[l * BATCH + b] = h;
                cnt += h;
            }
        }
    }
    __shared__ float c4[4];
    if (lane == 0) c4[w] = cnt;
    __syncthreads();
    if (threadIdx.x == 0)
        atomicAdd(&sums[b * SUMS_STRIDE], c4[0] + c4[1] + c4[2] + c4[3]);
}

// Kernel C1: partial ct sums, no atomics.
// block = (b, chunk of 64 l's); wave w handles 16 rows; LDS cross-wave reduce;
// partial written to part[(chunk*64+b)*256 + d].
__global__ __launch_bounds__(256) void ct_part_kernel(
    const float* __restrict__ ctx_val, const float* __restrict__ hard_raw,
    float* __restrict__ part) {
    int b     = blockIdx.x & 63;
    int chunk = blockIdx.x >> 6;
    int w     = threadIdx.x >> 6;
    int lane  = threadIdx.x & 63;
    int d0    = lane << 2;
    int l0    = chunk * 64 + w * 16;

    float h[16];
    #pragma unroll
    for (int i = 0; i < 16; i++) h[i] = hard_raw[(l0 + i) * BATCH + b];

    float4 acc = make_float4(0.f, 0.f, 0.f, 0.f);
    #pragma unroll 4
    for (int i = 0; i < 16; i++) {
        if (h[i] != 0.f) {                 // wave-uniform skip of the 1KB row
            int l = l0 + i;
            float4 v = *(const float4*)(ctx_val + (size_t)(l * BATCH + b) * DIM + d0);
            acc.x += v.x * h[i]; acc.y += v.y * h[i];
            acc.z += v.z * h[i]; acc.w += v.w * h[i];
        }
    }
    __shared__ float red[4 * DIM];
    *(float4*)(red + w * DIM + d0) = acc;
    __syncthreads();
    int d = threadIdx.x;
    float s = red[d] + red[DIM + d] + red[2 * DIM + d] + red[3 * DIM + d];
    part[(size_t)(chunk * BATCH + b) * DIM + d] = s;
}

// Kernel C2: ct[b][d] = (sum_chunk part) / (Z_b + 1e-10). 64 blocks.
__global__ __launch_bounds__(256) void ct_reduce_kernel(
    const float* __restrict__ part, const float* __restrict__ sums,
    float* __restrict__ ct) {
    int b = blockIdx.x;
    int d = threadIdx.x;
    float s = 0.f;
    #pragma unroll 8
    for (int c = 0; c < 32; c++)
        s += part[(size_t)(c * BATCH + b) * DIM + d];
    float invZ = 1.0f / (sums[b * SUMS_STRIDE] + 1e-10f);
    ct[b * DIM + d] = s * invZ;
}

// Kernel D: out_hard[l][b] = hard_raw[l][b] / (Z_b + 1e-10)
__global__ __launch_bounds__(256) void norm_kernel(
    const float* __restrict__ hard_raw, const float* __restrict__ sums,
    float* __restrict__ out_hard) {
    int i = blockIdx.x * blockDim.x + threadIdx.x;   // 4 elems each
    float4 h = *(const float4*)(hard_raw + (size_t)i * 4);
    int b0 = (i * 4) & 63;
    float4 o;
    o.x = h.x / (sums[(b0 + 0) * SUMS_STRIDE] + 1e-10f);
    o.y = h.y / (sums[(b0 + 1) * SUMS_STRIDE] + 1e-10f);
    o.z = h.z / (sums[(b0 + 2) * SUMS_STRIDE] + 1e-10f);
    o.w = h.w / (sums[(b0 + 3) * SUMS_STRIDE] + 1e-10f);
    *(float4*)(out_hard + (size_t)i * 4) = o;
}

extern "C" void kernel_launch(void* const* d_in, const int* in_sizes, int n_in,
                              void* d_out, int out_size, void* d_ws, size_t ws_size,
                              hipStream_t stream) {
    const float* ctx_val    = (const float*)d_in[0];
    const float* ctx_key    = (const float*)d_in[1];
    const float* ctx_mask   = (const float*)d_in[2];
    const float* att_past   = (const float*)d_in[3];
    const float* ht_query   = (const float*)d_in[4];
    const float* W_conv     = (const float*)d_in[5];
    const float* W_query    = (const float*)d_in[6];
    const float* W_att_past = (const float*)d_in[7];
    const float* b_att_past = (const float*)d_in[8];
    const float* W_attn     = (const float*)d_in[9];
    const float* b_attn     = (const float*)d_in[10];

    float* ws   = (float*)d_ws;
    float* hq   = ws + HQ_OFF;
    float* wf   = ws + WF_OFF;
    float* sums = ws + SUMS_OFF;
    float* hard = ws + HARD_OFF;
    float* part = ws + PART_OFF;

    float* out_ct   = (float*)d_out;                 // (64,256)
    float* out_hard = (float*)d_out + BATCH * DIM;   // (2048,64)

    hipMemsetAsync(sums, 0, BATCH * SUMS_STRIDE * sizeof(float), stream);

    prep_kernel<<<BATCH + 3, 256, 0, stream>>>(ht_query, W_query, W_conv, W_att_past, hq, wf);

    score_kernel<<<BATCH * 32, 256, 0, stream>>>(
        ctx_key, ctx_mask, att_past, hq, wf, b_att_past, W_attn, b_attn, hard, sums);

    ct_part_kernel<<<BATCH * 32, 256, 0, stream>>>(ctx_val, hard, part);

    ct_reduce_kernel<<<BATCH, 256, 0, stream>>>(part, sums, out_ct);

    norm_kernel<<<(L_MAX * BATCH) / (4 * 256), 256, 0, stream>>>(hard, sums, out_hard);
}